// Round 1
// baseline (1142.642 us; speedup 1.0000x reference)
//
#include <hip/hip_runtime.h>
#include <hip/hip_bf16.h>

#define T_LEN 2048
#define NSTATE 64

// Butterfly sum across all 64 lanes; every lane gets the total.
__device__ __forceinline__ float wave_sum64(float v) {
    #pragma unroll
    for (int d = 1; d < 64; d <<= 1) v += __shfl_xor(v, d, 64);
    return v;
}

// GEN_POLY = ('1111001','1011011'), mu=6, NS=64.
// State s = shift register, most-recent bit = MSB (bit 5).
// o0 parity bits of s: {5,4,3,0} -> mask 57 ; o1: {4,3,1,0} -> mask 27.
// gamma(s, b=0) = exp(0.5*(la + c0*l0 + c1*l1)),  gamma(s, b=1) = 1/gamma(s, b=0).
__global__ __launch_bounds__(128, 1)
void bcjr_kernel(const float* __restrict__ llr_ch,   // [B][2*T]
                 const float* __restrict__ llr_a,    // [B][T]
                 float* __restrict__ out,            // [B][T]
                 __hip_bfloat16* __restrict__ ws)    // [B][T][64]
{
    const int b    = blockIdx.x;
    const int wave = threadIdx.x >> 6;   // 0 = forward(alpha), 1 = backward(beta)
    const int lane = threadIdx.x & 63;   // = trellis state

    const float c0 = 1.0f - 2.0f * (float)(__popc(lane & 57) & 1);
    const float c1 = 1.0f - 2.0f * (float)(__popc(lane & 27) & 1);

    const float* ch  = llr_ch + (size_t)b * (2 * T_LEN);
    const float* lap = llr_a  + (size_t)b * T_LEN;
    float* ob        = out    + (size_t)b * T_LEN;
    __hip_bfloat16* w = ws + (size_t)b * T_LEN * NSTATE;

    const int Th = T_LEN / 2;

    // forward gather: alpha_new[j] = sum over preds 2*(j&31), 2*(j&31)+1, bit = j>>5
    const int  fs0 = 2 * (lane & 31);
    const int  fs1 = fs0 + 1;
    const bool fhi = (lane >= 32);
    // backward gather: successors of s are s>>1 (b=0) and 32|(s>>1) (b=1)
    const int  bs0 = lane >> 1;
    const int  bs1 = 32 + (lane >> 1);

    float state;

    // ---------------- Phase 1: half-sweeps, store state trajectory ----------------
    if (wave == 0) {
        state = (lane == 0) ? 1.0f : 0.0f;   // alpha0 = delta at state 0
        float pl0 = ch[0], pl1 = ch[1], pla = lap[0];
        for (int t = 0; t < Th; ++t) {
            float l0 = pl0, l1 = pl1, la = pla;
            int tn = t + 1;                       // prefetch next step's inputs
            pl0 = ch[2 * tn]; pl1 = ch[2 * tn + 1]; pla = lap[tn];
            w[(size_t)t * NSTATE + lane] = __float2bfloat16(state);  // alphas[t]
            float e  = 0.5f * (la + c0 * l0 + c1 * l1);
            float g0 = __expf(e);
            float g1 = __builtin_amdgcn_rcpf(g0);
            float v0 = state * g0;
            float v1 = state * g1;
            float a00 = __shfl(v0, fs0, 64);
            float a01 = __shfl(v0, fs1, 64);
            float a10 = __shfl(v1, fs0, 64);
            float a11 = __shfl(v1, fs1, 64);
            float an  = fhi ? (a10 + a11) : (a00 + a01);
            float s   = wave_sum64(an);
            state = an * __builtin_amdgcn_rcpf(s);
        }
    } else {
        state = 1.0f / 64.0f;                 // beta_T uniform
        float pl0 = ch[2 * (T_LEN - 1)], pl1 = ch[2 * (T_LEN - 1) + 1], pla = lap[T_LEN - 1];
        for (int t = T_LEN - 1; t >= Th; --t) {
            float l0 = pl0, l1 = pl1, la = pla;
            int tn = t - 1;
            pl0 = ch[2 * tn]; pl1 = ch[2 * tn + 1]; pla = lap[tn];
            w[(size_t)t * NSTATE + lane] = __float2bfloat16(state);  // betas[t+1]
            float e  = 0.5f * (la + c0 * l0 + c1 * l1);
            float g0 = __expf(e);
            float g1 = __builtin_amdgcn_rcpf(g0);
            float t0 = __shfl(state, bs0, 64);
            float t1 = __shfl(state, bs1, 64);
            float bn = g0 * t0 + g1 * t1;
            float s  = wave_sum64(bn);
            state = bn * __builtin_amdgcn_rcpf(s);
        }
    }

    __syncthreads();   // phase 1 global stores visible within block

    // ---------------- Phase 2: continue sweeps, combine + emit LLRs ----------------
    if (wave == 0) {
        // t in [Th, T): current state == alphas[t]; stored slot t holds betas[t+1]
        float pl0 = ch[2 * Th], pl1 = ch[2 * Th + 1], pla = lap[Th];
        float pbeta = __bfloat162float(w[(size_t)Th * NSTATE + lane]);
        for (int t = Th; t < T_LEN; ++t) {
            float l0 = pl0, l1 = pl1, la = pla, bnv = pbeta;
            int tn = t + 1;
            if (tn < T_LEN) {
                pl0 = ch[2 * tn]; pl1 = ch[2 * tn + 1]; pla = lap[tn];
                pbeta = __bfloat162float(w[(size_t)tn * NSTATE + lane]);
            }
            float e  = 0.5f * (la + c0 * l0 + c1 * l1);
            float g0 = __expf(e);
            float g1 = __builtin_amdgcn_rcpf(g0);
            float t0 = __shfl(bnv, bs0, 64);
            float t1 = __shfl(bnv, bs1, 64);
            float bg0 = g0 * t0;
            float bg1 = g1 * t1;
            float n0 = wave_sum64(state * bg0);
            float n1 = wave_sum64(state * bg1);
            if (lane == 0) ob[t] = __logf(n0) - __logf(n1);
            // advance alpha
            float v0 = state * g0;
            float v1 = state * g1;
            float a00 = __shfl(v0, fs0, 64);
            float a01 = __shfl(v0, fs1, 64);
            float a10 = __shfl(v1, fs0, 64);
            float a11 = __shfl(v1, fs1, 64);
            float an  = fhi ? (a10 + a11) : (a00 + a01);
            float s   = wave_sum64(an);
            state = an * __builtin_amdgcn_rcpf(s);
        }
    } else {
        // t in [Th-1 .. 0]: current state == betas[t+1]; stored slot t holds alphas[t]
        float pl0 = ch[2 * (Th - 1)], pl1 = ch[2 * (Th - 1) + 1], pla = lap[Th - 1];
        float palpha = __bfloat162float(w[(size_t)(Th - 1) * NSTATE + lane]);
        for (int t = Th - 1; t >= 0; --t) {
            float l0 = pl0, l1 = pl1, la = pla, av = palpha;
            int tn = t - 1;
            if (tn >= 0) {
                pl0 = ch[2 * tn]; pl1 = ch[2 * tn + 1]; pla = lap[tn];
                palpha = __bfloat162float(w[(size_t)tn * NSTATE + lane]);
            }
            float e  = 0.5f * (la + c0 * l0 + c1 * l1);
            float g0 = __expf(e);
            float g1 = __builtin_amdgcn_rcpf(g0);
            float t0 = __shfl(state, bs0, 64);
            float t1 = __shfl(state, bs1, 64);
            float bg0 = g0 * t0;
            float bg1 = g1 * t1;
            float n0 = wave_sum64(av * bg0);
            float n1 = wave_sum64(av * bg1);
            if (lane == 0) ob[t] = __logf(n0) - __logf(n1);
            // advance beta
            float bn = bg0 + bg1;
            float s  = wave_sum64(bn);
            state = bn * __builtin_amdgcn_rcpf(s);
        }
    }
}

extern "C" void kernel_launch(void* const* d_in, const int* in_sizes, int n_in,
                              void* d_out, int out_size, void* d_ws, size_t ws_size,
                              hipStream_t stream) {
    const float* llr_ch = (const float*)d_in[0];
    const float* llr_a  = (const float*)d_in[1];
    float* out = (float*)d_out;
    __hip_bfloat16* ws = (__hip_bfloat16*)d_ws;

    int B = in_sizes[0] / (2 * T_LEN);   // 256
    dim3 grid(B), block(128);
    hipLaunchKernelGGL(bcjr_kernel, grid, block, 0, stream, llr_ch, llr_a, out, ws);
}

// Round 2
// 455.365 us; speedup vs baseline: 2.5093x; 2.5093x over previous
//
#include <hip/hip_runtime.h>
#include <hip/hip_bf16.h>

#define T_LEN 2048
#define NSTATE 64
#define RENORM_K 8   // renorm every 8 steps; worst-case growth e^~68 < fp32 max

// Butterfly sum across all 64 lanes; every lane gets the total.
__device__ __forceinline__ float wave_sum64(float v) {
    #pragma unroll
    for (int d = 1; d < 64; d <<= 1) v += __shfl_xor(v, d, 64);
    return v;
}

// GEN_POLY = ('1111001','1011011'), mu=6, NS=64.
// State s = shift register, most-recent bit = MSB (bit 5).
// o0 parity bits of s: {5,4,3,0} -> mask 57 ; o1: {4,3,1,0} -> mask 27.
// gamma(s, b=0) = exp(0.5*(la + c0*l0 + c1*l1)), gamma(s, b=1) = 1/gamma(s, b=0).

// ---------------- Kernel A: sequential sweeps, trajectories only ----------------
// wave0: full alpha sweep t=0..T-1, stores alpha_t (bf16) to wsA[b][t][:]
// wave1: full beta  sweep t=T-1..0, stores beta_{t+1} (bf16) to wsB[b][t][:]
// No LLR work on the critical waves; renorm amortized every RENORM_K steps.
__global__ __launch_bounds__(128, 1)
void bcjr_sweep_kernel(const float* __restrict__ llr_ch,   // [B][2*T]
                       const float* __restrict__ llr_a,    // [B][T]
                       __hip_bfloat16* __restrict__ wsA,   // [B][T][64]
                       __hip_bfloat16* __restrict__ wsB)   // [B][T][64]
{
    const int b    = blockIdx.x;
    const int wave = threadIdx.x >> 6;
    const int lane = threadIdx.x & 63;

    const float c0 = 1.0f - 2.0f * (float)(__popc(lane & 57) & 1);
    const float c1 = 1.0f - 2.0f * (float)(__popc(lane & 27) & 1);

    const float* ch  = llr_ch + (size_t)b * (2 * T_LEN);
    const float* lap = llr_a  + (size_t)b * T_LEN;

    if (wave == 0) {
        __hip_bfloat16* w = wsA + (size_t)b * T_LEN * NSTATE;
        // forward gather: alpha_new[j] = v_{j>>5}[2*(j&31)] + v_{j>>5}[2*(j&31)+1]
        const int  fs0 = 2 * (lane & 31);
        const int  fs1 = fs0 + 1;
        const bool fhi = (lane >= 32);
        float state = (lane == 0) ? 1.0f : 0.0f;
        float pl0 = ch[0], pl1 = ch[1], pla = lap[0];
        for (int t = 0; t < T_LEN; ++t) {
            float l0 = pl0, l1 = pl1, la = pla;
            int tn = t + 1;
            if (tn < T_LEN) { pl0 = ch[2 * tn]; pl1 = ch[2 * tn + 1]; pla = lap[tn]; }
            w[(size_t)t * NSTATE + lane] = __float2bfloat16(state);   // alpha_t
            float e  = 0.5f * (la + c0 * l0 + c1 * l1);
            float g0 = __expf(e);
            float g1 = __builtin_amdgcn_rcpf(g0);
            float v0 = state * g0;
            float v1 = state * g1;
            float a00 = __shfl(v0, fs0, 64);
            float a01 = __shfl(v0, fs1, 64);
            float a10 = __shfl(v1, fs0, 64);
            float a11 = __shfl(v1, fs1, 64);
            float an  = fhi ? (a10 + a11) : (a00 + a01);
            if ((t & (RENORM_K - 1)) == (RENORM_K - 1)) {
                float s = wave_sum64(an);
                an = an * __builtin_amdgcn_rcpf(s);
            }
            state = an;
        }
    } else {
        __hip_bfloat16* w = wsB + (size_t)b * T_LEN * NSTATE;
        // backward gather: successors of s are s>>1 (b=0) and 32|(s>>1) (b=1)
        const int bs0 = lane >> 1;
        const int bs1 = 32 + (lane >> 1);
        float state = 1.0f / 64.0f;   // beta_T uniform
        float pl0 = ch[2 * (T_LEN - 1)], pl1 = ch[2 * (T_LEN - 1) + 1], pla = lap[T_LEN - 1];
        for (int t = T_LEN - 1; t >= 0; --t) {
            float l0 = pl0, l1 = pl1, la = pla;
            int tn = t - 1;
            if (tn >= 0) { pl0 = ch[2 * tn]; pl1 = ch[2 * tn + 1]; pla = lap[tn]; }
            w[(size_t)t * NSTATE + lane] = __float2bfloat16(state);   // beta_{t+1}
            float e  = 0.5f * (la + c0 * l0 + c1 * l1);
            float g0 = __expf(e);
            float g1 = __builtin_amdgcn_rcpf(g0);
            float t0 = __shfl(state, bs0, 64);
            float t1 = __shfl(state, bs1, 64);
            float bn = g0 * t0 + g1 * t1;
            if ((t & (RENORM_K - 1)) == 0) {
                float s = wave_sum64(bn);
                bn = bn * __builtin_amdgcn_rcpf(s);
            }
            state = bn;
        }
    }
}

// ---------------- Kernel B: fully parallel LLR computation ----------------
// One wave per (b,t). lane = state s.
// llr_t = log(sum_s a[s] g0[s] B[s>>1]) - log(sum_s a[s] g1[s] B[32|(s>>1)])
__global__ __launch_bounds__(256, 4)
void bcjr_llr_kernel(const float* __restrict__ llr_ch,
                     const float* __restrict__ llr_a,
                     const __hip_bfloat16* __restrict__ wsA,
                     const __hip_bfloat16* __restrict__ wsB,
                     float* __restrict__ out)
{
    const int wid  = blockIdx.x * 4 + (threadIdx.x >> 6);
    const int lane = threadIdx.x & 63;
    const int b    = wid >> 11;            // T_LEN = 2048
    const int t    = wid & (T_LEN - 1);

    const float c0 = 1.0f - 2.0f * (float)(__popc(lane & 57) & 1);
    const float c1 = 1.0f - 2.0f * (float)(__popc(lane & 27) & 1);

    float alpha = __bfloat162float(wsA[((size_t)b * T_LEN + t) * NSTATE + lane]);
    float beta  = __bfloat162float(wsB[((size_t)b * T_LEN + t) * NSTATE + lane]);
    float l0 = llr_ch[(size_t)b * 2 * T_LEN + 2 * t];
    float l1 = llr_ch[(size_t)b * 2 * T_LEN + 2 * t + 1];
    float la = llr_a [(size_t)b * T_LEN + t];

    // normalize alpha so alpha*g*beta stays in fp32 range (beta can be ~5e29)
    float sa = wave_sum64(alpha);
    alpha = alpha * __builtin_amdgcn_rcpf(sa);

    float e  = 0.5f * (la + c0 * l0 + c1 * l1);
    float g0 = __expf(e);
    float g1 = __builtin_amdgcn_rcpf(g0);
    float t0 = __shfl(beta, lane >> 1, 64);
    float t1 = __shfl(beta, 32 + (lane >> 1), 64);
    float n0 = wave_sum64(alpha * g0 * t0);
    float n1 = wave_sum64(alpha * g1 * t1);
    if (lane == 0) out[(size_t)b * T_LEN + t] = __logf(n0) - __logf(n1);
}

// ---------------- Fallback (round-1 fused kernel) for small ws ----------------
__global__ __launch_bounds__(128, 1)
void bcjr_fused_kernel(const float* __restrict__ llr_ch,
                       const float* __restrict__ llr_a,
                       float* __restrict__ out,
                       __hip_bfloat16* __restrict__ ws)
{
    const int b    = blockIdx.x;
    const int wave = threadIdx.x >> 6;
    const int lane = threadIdx.x & 63;

    const float c0 = 1.0f - 2.0f * (float)(__popc(lane & 57) & 1);
    const float c1 = 1.0f - 2.0f * (float)(__popc(lane & 27) & 1);

    const float* ch  = llr_ch + (size_t)b * (2 * T_LEN);
    const float* lap = llr_a  + (size_t)b * T_LEN;
    float* ob        = out    + (size_t)b * T_LEN;
    __hip_bfloat16* w = ws + (size_t)b * T_LEN * NSTATE;

    const int Th = T_LEN / 2;
    const int  fs0 = 2 * (lane & 31);
    const int  fs1 = fs0 + 1;
    const bool fhi = (lane >= 32);
    const int  bs0 = lane >> 1;
    const int  bs1 = 32 + (lane >> 1);
    float state;

    if (wave == 0) {
        state = (lane == 0) ? 1.0f : 0.0f;
        float pl0 = ch[0], pl1 = ch[1], pla = lap[0];
        for (int t = 0; t < Th; ++t) {
            float l0 = pl0, l1 = pl1, la = pla;
            int tn = t + 1;
            pl0 = ch[2 * tn]; pl1 = ch[2 * tn + 1]; pla = lap[tn];
            w[(size_t)t * NSTATE + lane] = __float2bfloat16(state);
            float e  = 0.5f * (la + c0 * l0 + c1 * l1);
            float g0 = __expf(e);
            float g1 = __builtin_amdgcn_rcpf(g0);
            float v0 = state * g0, v1 = state * g1;
            float a00 = __shfl(v0, fs0, 64), a01 = __shfl(v0, fs1, 64);
            float a10 = __shfl(v1, fs0, 64), a11 = __shfl(v1, fs1, 64);
            float an  = fhi ? (a10 + a11) : (a00 + a01);
            float s   = wave_sum64(an);
            state = an * __builtin_amdgcn_rcpf(s);
        }
    } else {
        state = 1.0f / 64.0f;
        float pl0 = ch[2 * (T_LEN - 1)], pl1 = ch[2 * (T_LEN - 1) + 1], pla = lap[T_LEN - 1];
        for (int t = T_LEN - 1; t >= Th; --t) {
            float l0 = pl0, l1 = pl1, la = pla;
            int tn = t - 1;
            pl0 = ch[2 * tn]; pl1 = ch[2 * tn + 1]; pla = lap[tn];
            w[(size_t)t * NSTATE + lane] = __float2bfloat16(state);
            float e  = 0.5f * (la + c0 * l0 + c1 * l1);
            float g0 = __expf(e);
            float g1 = __builtin_amdgcn_rcpf(g0);
            float t0 = __shfl(state, bs0, 64), t1 = __shfl(state, bs1, 64);
            float bn = g0 * t0 + g1 * t1;
            float s  = wave_sum64(bn);
            state = bn * __builtin_amdgcn_rcpf(s);
        }
    }
    __syncthreads();
    if (wave == 0) {
        float pl0 = ch[2 * Th], pl1 = ch[2 * Th + 1], pla = lap[Th];
        float pbeta = __bfloat162float(w[(size_t)Th * NSTATE + lane]);
        for (int t = Th; t < T_LEN; ++t) {
            float l0 = pl0, l1 = pl1, la = pla, bnv = pbeta;
            int tn = t + 1;
            if (tn < T_LEN) {
                pl0 = ch[2 * tn]; pl1 = ch[2 * tn + 1]; pla = lap[tn];
                pbeta = __bfloat162float(w[(size_t)tn * NSTATE + lane]);
            }
            float e  = 0.5f * (la + c0 * l0 + c1 * l1);
            float g0 = __expf(e);
            float g1 = __builtin_amdgcn_rcpf(g0);
            float t0 = __shfl(bnv, bs0, 64), t1 = __shfl(bnv, bs1, 64);
            float bg0 = g0 * t0, bg1 = g1 * t1;
            float n0 = wave_sum64(state * bg0);
            float n1 = wave_sum64(state * bg1);
            if (lane == 0) ob[t] = __logf(n0) - __logf(n1);
            float v0 = state * g0, v1 = state * g1;
            float a00 = __shfl(v0, fs0, 64), a01 = __shfl(v0, fs1, 64);
            float a10 = __shfl(v1, fs0, 64), a11 = __shfl(v1, fs1, 64);
            float an  = fhi ? (a10 + a11) : (a00 + a01);
            float s   = wave_sum64(an);
            state = an * __builtin_amdgcn_rcpf(s);
        }
    } else {
        float pl0 = ch[2 * (Th - 1)], pl1 = ch[2 * (Th - 1) + 1], pla = lap[Th - 1];
        float palpha = __bfloat162float(w[(size_t)(Th - 1) * NSTATE + lane]);
        for (int t = Th - 1; t >= 0; --t) {
            float l0 = pl0, l1 = pl1, la = pla, av = palpha;
            int tn = t - 1;
            if (tn >= 0) {
                pl0 = ch[2 * tn]; pl1 = ch[2 * tn + 1]; pla = lap[tn];
                palpha = __bfloat162float(w[(size_t)tn * NSTATE + lane]);
            }
            float e  = 0.5f * (la + c0 * l0 + c1 * l1);
            float g0 = __expf(e);
            float g1 = __builtin_amdgcn_rcpf(g0);
            float t0 = __shfl(state, bs0, 64), t1 = __shfl(state, bs1, 64);
            float bg0 = g0 * t0, bg1 = g1 * t1;
            float n0 = wave_sum64(av * bg0);
            float n1 = wave_sum64(av * bg1);
            if (lane == 0) ob[t] = __logf(n0) - __logf(n1);
            float bn = bg0 + bg1;
            float s  = wave_sum64(bn);
            state = bn * __builtin_amdgcn_rcpf(s);
        }
    }
}

extern "C" void kernel_launch(void* const* d_in, const int* in_sizes, int n_in,
                              void* d_out, int out_size, void* d_ws, size_t ws_size,
                              hipStream_t stream) {
    const float* llr_ch = (const float*)d_in[0];
    const float* llr_a  = (const float*)d_in[1];
    float* out = (float*)d_out;

    int B = in_sizes[0] / (2 * T_LEN);   // 256
    const size_t traj_bytes = (size_t)B * T_LEN * NSTATE * sizeof(__hip_bfloat16); // 64 MiB

    if (ws_size >= 2 * traj_bytes) {
        __hip_bfloat16* wsA = (__hip_bfloat16*)d_ws;
        __hip_bfloat16* wsB = (__hip_bfloat16*)((char*)d_ws + traj_bytes);
        hipLaunchKernelGGL(bcjr_sweep_kernel, dim3(B), dim3(128), 0, stream,
                           llr_ch, llr_a, wsA, wsB);
        int n_waves = B * T_LEN;          // one wave per (b,t)
        hipLaunchKernelGGL(bcjr_llr_kernel, dim3(n_waves / 4), dim3(256), 0, stream,
                           llr_ch, llr_a, wsA, wsB, out);
    } else {
        hipLaunchKernelGGL(bcjr_fused_kernel, dim3(B), dim3(128), 0, stream,
                           llr_ch, llr_a, out, (__hip_bfloat16*)d_ws);
    }
}

// Round 4
// 183.849 us; speedup vs baseline: 6.2151x; 2.4768x over previous
//
#include <hip/hip_runtime.h>
#include <hip/hip_bf16.h>

#define T_LEN 2048
#define NSTATE 64
#define NCHUNK 16
#define CH_S (T_LEN / NCHUNK)   // 128 stored steps per chunk
#define WARM 128                // warm-up steps (21*mu) before the stored region
#define RK 16                   // renorm every 16 steps (scale cancels in LLR)

// Butterfly sum across all 64 lanes; every lane gets the total.
__device__ __forceinline__ float wave_sum64(float v) {
    #pragma unroll
    for (int d = 1; d < 64; d <<= 1) v += __shfl_xor(v, d, 64);
    return v;
}

// v + v[lane^1] via DPP quad_perm [1,0,3,2] — VALU pipe, no DS op.
__device__ __forceinline__ float pair_sum_xor1(float v) {
    int r = __builtin_amdgcn_update_dpp(0, __float_as_int(v), 0xB1, 0xF, 0xF, true);
    return v + __int_as_float(r);
}

__device__ __forceinline__ float bf16_lo(unsigned u) { return __uint_as_float(u << 16); }
__device__ __forceinline__ float bf16_hi(unsigned u) { return __uint_as_float(u & 0xffff0000u); }

// GEN_POLY = ('1111001','1011011'), mu=6, NS=64.
// State s = shift register, most-recent bit = MSB (bit 5).
// o0 parity bits of s: {5,4,3,0} -> mask 57 ; o1: {4,3,1,0} -> mask 27.
// gamma(s,b=0) = exp(0.5*(la + c0*l0 + c1*l1)) = exp(e_s); gamma(s,b=1) = exp(-e_s).

// ---------------- Kernel A: chunked sweeps with warm-up ----------------
// 2*NCHUNK waves per sequence: dir0 = alpha chunk, dir1 = beta chunk.
// Each wave: WARM steps from uniform init (exact init at sequence edges),
// then CH_S stored steps. lane = trellis state. Stores bf16 trajectories.
__global__ __launch_bounds__(256, 8)
void bcjr_sweep_kernel(const float* __restrict__ llr_ch,   // [B][2*T]
                       const float* __restrict__ llr_a,    // [B][T]
                       __hip_bfloat16* __restrict__ wsA,   // [B][T][64] bf16 alpha_t
                       __hip_bfloat16* __restrict__ wsB)   // [B][T][64] bf16 beta_{t+1}
{
    const int wave  = blockIdx.x * 4 + (threadIdx.x >> 6);
    const int lane  = threadIdx.x & 63;
    const int dir   = wave & 1;
    const int chunk = (wave >> 1) & (NCHUNK - 1);
    const int b     = wave >> 5;          // log2(2*NCHUNK) = 5

    const float c0 = 1.0f - 2.0f * (float)(__popc(lane & 57) & 1);
    const float c1 = 1.0f - 2.0f * (float)(__popc(lane & 27) & 1);

    const float2* ch = (const float2*)(llr_ch + (size_t)b * (2 * T_LEN));
    const float*  lap = llr_a + (size_t)b * T_LEN;

    if (dir == 0) {
        // ---- alpha: forward. alpha_new[j] = sum over preds 2*(j&31)+{0,1}, bit j>>5
        __hip_bfloat16* w = wsA + (size_t)b * T_LEN * NSTATE;
        const int  fs0 = 2 * (lane & 31);
        const bool fhi = (lane >= 32);
        const int t0 = chunk * CH_S;
        const int ts = (chunk == 0) ? 0 : t0 - WARM;
        const int te = t0 + CH_S;
        float state = (chunk == 0) ? ((lane == 0) ? 1.0f : 0.0f) : (1.0f / 64.0f);
        float2 pc = ch[ts];
        float  pla = lap[ts];
        for (int t = ts; t < te; ++t) {
            float l0 = pc.x, l1 = pc.y, la = pla;
            int tn = t + 1;
            if (tn < T_LEN) { pc = ch[tn]; pla = lap[tn]; }
            if (t >= t0) w[(size_t)t * NSTATE + lane] = __float2bfloat16(state);
            float e  = 0.5f * (la + c0 * l0 + c1 * l1);
            float g0 = __expf(e);
            float g1 = __builtin_amdgcn_rcpf(g0);
            float s0 = pair_sum_xor1(state * g0);   // even lanes 2m: v0[2m]+v0[2m+1]
            float s1 = pair_sum_xor1(state * g1);
            float a0 = __shfl(s0, fs0, 64);
            float a1 = __shfl(s1, fs0, 64);
            float an = fhi ? a1 : a0;
            if ((t & (RK - 1)) == (RK - 1)) {
                float s = wave_sum64(an);
                an = an * __builtin_amdgcn_rcpf(s);
            }
            state = an;
        }
    } else {
        // ---- beta: backward. successors of s: s>>1 (b=0), 32|(s>>1) (b=1)
        __hip_bfloat16* w = wsB + (size_t)b * T_LEN * NSTATE;
        const int bs0 = lane >> 1;
        const int bs1 = 32 + (lane >> 1);
        const int t0 = chunk * CH_S;                       // store range [t0, t0+CH_S)
        const int thi = (chunk == NCHUNK - 1) ? (T_LEN - 1) : (t0 + CH_S - 1 + WARM);
        float state = 1.0f / 64.0f;   // exact beta_T for last chunk; warm init otherwise
        float2 pc = ch[thi];
        float  pla = lap[thi];
        for (int t = thi; t >= t0; --t) {
            float l0 = pc.x, l1 = pc.y, la = pla;
            int tn = t - 1;
            if (tn >= 0) { pc = ch[tn]; pla = lap[tn]; }
            if (t < t0 + CH_S) w[(size_t)t * NSTATE + lane] = __float2bfloat16(state);
            float e  = 0.5f * (la + c0 * l0 + c1 * l1);
            float g0 = __expf(e);
            float g1 = __builtin_amdgcn_rcpf(g0);
            float t0v = __shfl(state, bs0, 64);
            float t1v = __shfl(state, bs1, 64);
            float bn = g0 * t0v + g1 * t1v;
            if ((t & (RK - 1)) == 0) {
                float s = wave_sum64(bn);
                bn = bn * __builtin_amdgcn_rcpf(s);
            }
            state = bn;
        }
    }
}

// ---------------- Kernel B: thread-per-(b,t) LLR, no cross-lane ops ----------------
// llr_t = log(sum_s a[s] g0[s] B[s>>1]) - log(sum_s a[s] g1[s] B[32|(s>>1)])
// Scales of unnormalized alpha/beta cancel exactly in the log-ratio.
__global__ __launch_bounds__(256, 4)
void bcjr_llr_kernel(const float* __restrict__ llr_ch,
                     const float* __restrict__ llr_a,
                     const __hip_bfloat16* __restrict__ wsA,
                     const __hip_bfloat16* __restrict__ wsB,
                     float* __restrict__ out)
{
    const int gid = blockIdx.x * 256 + threadIdx.x;      // = b*T + t

    const uint4* ap = (const uint4*)(wsA + (size_t)gid * NSTATE);
    const uint4* bp = (const uint4*)(wsB + (size_t)gid * NSTATE);
    unsigned Aw[32], Bw[32];
    #pragma unroll
    for (int k = 0; k < 8; ++k) {
        uint4 v = ap[k];
        Aw[4 * k] = v.x; Aw[4 * k + 1] = v.y; Aw[4 * k + 2] = v.z; Aw[4 * k + 3] = v.w;
    }
    #pragma unroll
    for (int k = 0; k < 8; ++k) {
        uint4 v = bp[k];
        Bw[4 * k] = v.x; Bw[4 * k + 1] = v.y; Bw[4 * k + 2] = v.z; Bw[4 * k + 3] = v.w;
    }

    float2 c2 = ((const float2*)llr_ch)[gid];
    float  la = llr_a[gid];
    float E = 0.5f * la, X0 = 0.5f * c2.x, X1 = 0.5f * c2.y;

    float G[4], R[4];
    G[0] = __expf(E + X0 + X1);     // p0=0,p1=0
    G[1] = __expf(E + X0 - X1);     // p0=0,p1=1
    G[2] = __expf(E - X0 + X1);     // p0=1,p1=0
    G[3] = __expf(E - X0 - X1);     // p0=1,p1=1
    #pragma unroll
    for (int k = 0; k < 4; ++k) R[k] = __builtin_amdgcn_rcpf(G[k]);

    float n0 = 0.0f, n1 = 0.0f;
    #pragma unroll
    for (int j = 0; j < 32; ++j) {
        // combo(2j): p0 = parity(j&28), p1 = parity(j&13); combo(2j+1) = combo ^ 3
        const int k0 = ((__popc(j & 28) & 1) << 1) | (__popc(j & 13) & 1);
        float a0 = bf16_lo(Aw[j]);          // alpha[2j]
        float a1 = bf16_hi(Aw[j]);          // alpha[2j+1]
        unsigned bd0 = Bw[j >> 1];          // beta[j]     (n0 path)
        unsigned bd1 = Bw[16 + (j >> 1)];   // beta[32+j]  (n1 path)
        float b0 = (j & 1) ? bf16_hi(bd0) : bf16_lo(bd0);
        float b1 = (j & 1) ? bf16_hi(bd1) : bf16_lo(bd1);
        n0 = fmaf(b0, fmaf(a0, G[k0], a1 * G[k0 ^ 3]), n0);
        n1 = fmaf(b1, fmaf(a0, R[k0], a1 * R[k0 ^ 3]), n1);
    }
    out[gid] = __logf(n0) - __logf(n1);
}

extern "C" void kernel_launch(void* const* d_in, const int* in_sizes, int n_in,
                              void* d_out, int out_size, void* d_ws, size_t ws_size,
                              hipStream_t stream) {
    const float* llr_ch = (const float*)d_in[0];
    const float* llr_a  = (const float*)d_in[1];
    float* out = (float*)d_out;

    int B = in_sizes[0] / (2 * T_LEN);   // 256
    const size_t traj_bytes = (size_t)B * T_LEN * NSTATE * sizeof(__hip_bfloat16); // 64 MiB

    __hip_bfloat16* wsA = (__hip_bfloat16*)d_ws;
    __hip_bfloat16* wsB = (__hip_bfloat16*)((char*)d_ws + traj_bytes);

    int n_waves = B * NCHUNK * 2;        // 8192 sweep waves
    hipLaunchKernelGGL(bcjr_sweep_kernel, dim3(n_waves / 4), dim3(256), 0, stream,
                       llr_ch, llr_a, wsA, wsB);

    int n_thr = B * T_LEN;               // one thread per (b,t)
    hipLaunchKernelGGL(bcjr_llr_kernel, dim3(n_thr / 256), dim3(256), 0, stream,
                       llr_ch, llr_a, wsA, wsB, out);
}

// Round 5
// 147.103 us; speedup vs baseline: 7.7677x; 1.2498x over previous
//
#include <hip/hip_runtime.h>
#include <hip/hip_bf16.h>

#define T_LEN 2048
#define NSTATE 64
#define NCHUNK 16
#define CH_S 128      // stored steps per chunk
#define WARM 64       // warm-up steps (10.7*mu) before the stored region
#define RK 16         // renorm every 16 steps (scale cancels in LLR)

// Butterfly sum across all 64 lanes; every lane gets the total.
__device__ __forceinline__ float wave_sum64(float v) {
    #pragma unroll
    for (int d = 1; d < 64; d <<= 1) v += __shfl_xor(v, d, 64);
    return v;
}

// v + v[lane^1] via DPP quad_perm [1,0,3,2] — VALU pipe, no DS op.
__device__ __forceinline__ float pair_sum_xor1(float v) {
    int r = __builtin_amdgcn_update_dpp(0, __float_as_int(v), 0xB1, 0xF, 0xF, true);
    return v + __int_as_float(r);
}

// cheap fp32 -> bf16 (round-half-up): 2 VALU ops, no NaN path
__device__ __forceinline__ unsigned short bf16_of(float f) {
    return (unsigned short)((__float_as_uint(f) + 0x8000u) >> 16);
}
__device__ __forceinline__ float bf16_lo(unsigned u) { return __uint_as_float(u << 16); }
__device__ __forceinline__ float bf16_hi(unsigned u) { return __uint_as_float(u & 0xffff0000u); }

// GEN_POLY = ('1111001','1011011'), mu=6, NS=64.
// State s: shift register, most-recent bit = MSB (bit 5).
// o0 parity mask of s: 57 ; o1 mask: 27.
// log2-domain branch metric: x_s = kE*la + (kE*c0)*l0 + (kE*c1)*l1, kE = 0.5*log2(e)
// gamma(s,0) = 2^x_s ; gamma(s,1) = 2^-x_s.

// ---------------- Kernel A: chunked sweeps, branchless 16-step groups ----------------
__global__ __launch_bounds__(256, 8)
void bcjr_sweep_kernel(const float* __restrict__ llr_ch,   // [B][2*T]
                       const float* __restrict__ llr_a,    // [B][T]
                       unsigned short* __restrict__ wsA,   // [B][T][64] bf16 alpha_t
                       unsigned short* __restrict__ wsB)   // [B][T][64] bf16 beta_{t+1}
{
    const int wave  = blockIdx.x * 4 + (threadIdx.x >> 6);
    const int lane  = threadIdx.x & 63;
    const int dir   = wave & 1;
    const int chunk = (wave >> 1) & (NCHUNK - 1);
    const int b     = wave >> 5;

    const float c0 = 1.0f - 2.0f * (float)(__popc(lane & 57) & 1);
    const float c1 = 1.0f - 2.0f * (float)(__popc(lane & 27) & 1);
    const float kE = 0.5f * 1.442695040888963f;
    const float k0 = kE * c0, k1 = kE * c1;

    const float* chp = llr_ch + (size_t)b * (2 * T_LEN);
    const float* lap = llr_a  + (size_t)b * T_LEN;

    if (dir == 0) {
        // ---- alpha forward: alpha_new[j] = sum preds 2*(j&31)+{0,1}, bit j>>5
        unsigned short* w = wsA + (size_t)b * T_LEN * NSTATE;
        const int  fs0 = 2 * (lane & 31);
        const bool fhi = (lane >= 32);
        const int t0 = chunk * CH_S;
        const int ts = (chunk == 0) ? t0 : t0 - WARM;
        float state = (chunk == 0) ? ((lane == 0) ? 1.0f : 0.0f) : (1.0f / 64.0f);

        for (int g = ts; g < t0 + CH_S; g += RK) {
            const bool store = (g >= t0);
            #pragma unroll
            for (int h = 0; h < 2; ++h) {
                const int gb = g + 8 * h;
                const float4* c4 = (const float4*)(chp + 2 * gb);
                const float4* a4 = (const float4*)(lap + gb);
                float4 cc[4], aa[2];
                #pragma unroll
                for (int i = 0; i < 4; ++i) cc[i] = c4[i];
                #pragma unroll
                for (int i = 0; i < 2; ++i) aa[i] = a4[i];
                unsigned short* wb = w + (size_t)gb * NSTATE + lane;
                #pragma unroll
                for (int i = 0; i < 8; ++i) {
                    float l0 = (i & 1) ? cc[i >> 1].z : cc[i >> 1].x;
                    float l1 = (i & 1) ? cc[i >> 1].w : cc[i >> 1].y;
                    float la = ((const float*)aa)[i];
                    if (store) wb[i * NSTATE] = bf16_of(state);   // alpha_t
                    float x   = fmaf(la, kE, fmaf(l0, k0, l1 * k1));
                    float g0v = exp2f(x);
                    float g1v = __builtin_amdgcn_rcpf(g0v);
                    float s0  = pair_sum_xor1(state * g0v);
                    float s1  = pair_sum_xor1(state * g1v);
                    float a0  = __shfl(s0, fs0, 64);
                    float a1  = __shfl(s1, fs0, 64);
                    state = fhi ? a1 : a0;
                }
            }
            float s = wave_sum64(state);
            state = state * __builtin_amdgcn_rcpf(s);
        }
    } else {
        // ---- beta backward: successors of s: s>>1 (b=0), 32|(s>>1) (b=1)
        unsigned short* w = wsB + (size_t)b * T_LEN * NSTATE;
        const int bs0 = lane >> 1;
        const int bs1 = 32 + (lane >> 1);
        const int t0 = chunk * CH_S;
        const int te = (chunk == NCHUNK - 1) ? (t0 + CH_S) : (t0 + CH_S + WARM);
        float state = 1.0f / 64.0f;   // exact beta_T at sequence end; warm init otherwise

        for (int g = te - RK; g >= t0; g -= RK) {
            const bool store = (g < t0 + CH_S);
            #pragma unroll
            for (int h = 1; h >= 0; --h) {
                const int gb = g + 8 * h;
                const float4* c4 = (const float4*)(chp + 2 * gb);
                const float4* a4 = (const float4*)(lap + gb);
                float4 cc[4], aa[2];
                #pragma unroll
                for (int i = 0; i < 4; ++i) cc[i] = c4[i];
                #pragma unroll
                for (int i = 0; i < 2; ++i) aa[i] = a4[i];
                unsigned short* wb = w + (size_t)gb * NSTATE + lane;
                #pragma unroll
                for (int i = 7; i >= 0; --i) {
                    float l0 = (i & 1) ? cc[i >> 1].z : cc[i >> 1].x;
                    float l1 = (i & 1) ? cc[i >> 1].w : cc[i >> 1].y;
                    float la = ((const float*)aa)[i];
                    if (store) wb[i * NSTATE] = bf16_of(state);   // beta_{t+1}
                    float x   = fmaf(la, kE, fmaf(l0, k0, l1 * k1));
                    float g0v = exp2f(x);
                    float g1v = __builtin_amdgcn_rcpf(g0v);
                    float t0v = __shfl(state, bs0, 64);
                    float t1v = __shfl(state, bs1, 64);
                    state = fmaf(g0v, t0v, g1v * t1v);
                }
            }
            float s = wave_sum64(state);
            state = state * __builtin_amdgcn_rcpf(s);
        }
    }
}

// ---------------- Kernel B: thread-per-(b,t) LLR, no cross-lane ops ----------------
// llr_t = log(sum_s a[s] g0[s] B[s>>1]) - log(sum_s a[s] g1[s] B[32|(s>>1)])
// Unnormalized scales cancel exactly in the log-ratio.
__global__ __launch_bounds__(256, 4)
void bcjr_llr_kernel(const float* __restrict__ llr_ch,
                     const float* __restrict__ llr_a,
                     const unsigned short* __restrict__ wsA,
                     const unsigned short* __restrict__ wsB,
                     float* __restrict__ out)
{
    const int gid = blockIdx.x * 256 + threadIdx.x;      // = b*T + t

    const uint4* ap = (const uint4*)(wsA + (size_t)gid * NSTATE);
    const uint4* bp = (const uint4*)(wsB + (size_t)gid * NSTATE);

    unsigned Bw[32];
    #pragma unroll
    for (int k = 0; k < 8; ++k) {
        uint4 v = bp[k];
        Bw[4 * k] = v.x; Bw[4 * k + 1] = v.y; Bw[4 * k + 2] = v.z; Bw[4 * k + 3] = v.w;
    }

    float2 c2 = ((const float2*)llr_ch)[gid];
    float  la = llr_a[gid];
    const float kE = 0.5f * 1.442695040888963f;
    float E = la * kE, X0 = c2.x * kE, X1 = c2.y * kE;

    float G[4], R[4];
    G[0] = exp2f(E + X0 + X1);     // p0=0,p1=0
    G[1] = exp2f(E + X0 - X1);     // p0=0,p1=1
    G[2] = exp2f(E - X0 + X1);     // p0=1,p1=0
    G[3] = exp2f(E - X0 - X1);     // p0=1,p1=1
    #pragma unroll
    for (int k = 0; k < 4; ++k) R[k] = __builtin_amdgcn_rcpf(G[k]);

    float n0 = 0.0f, n1 = 0.0f;
    #pragma unroll
    for (int k = 0; k < 8; ++k) {          // stream alpha, 4 dwords at a time
        uint4 av = ap[k];
        unsigned aw[4] = { av.x, av.y, av.z, av.w };
        #pragma unroll
        for (int m = 0; m < 4; ++m) {
            const int j = 4 * k + m;
            const int k0 = ((__popc(j & 28) & 1) << 1) | (__popc(j & 13) & 1);
            float a0 = bf16_lo(aw[m]);          // alpha[2j]
            float a1 = bf16_hi(aw[m]);          // alpha[2j+1]
            unsigned bd0 = Bw[j >> 1];          // beta[j]     (n0 path)
            unsigned bd1 = Bw[16 + (j >> 1)];   // beta[32+j]  (n1 path)
            float b0 = (j & 1) ? bf16_hi(bd0) : bf16_lo(bd0);
            float b1 = (j & 1) ? bf16_hi(bd1) : bf16_lo(bd1);
            n0 = fmaf(b0, fmaf(a0, G[k0], a1 * G[k0 ^ 3]), n0);
            n1 = fmaf(b1, fmaf(a0, R[k0], a1 * R[k0 ^ 3]), n1);
        }
    }
    out[gid] = __logf(n0) - __logf(n1);
}

extern "C" void kernel_launch(void* const* d_in, const int* in_sizes, int n_in,
                              void* d_out, int out_size, void* d_ws, size_t ws_size,
                              hipStream_t stream) {
    const float* llr_ch = (const float*)d_in[0];
    const float* llr_a  = (const float*)d_in[1];
    float* out = (float*)d_out;

    int B = in_sizes[0] / (2 * T_LEN);   // 256
    const size_t traj_bytes = (size_t)B * T_LEN * NSTATE * sizeof(unsigned short); // 64 MiB

    unsigned short* wsA = (unsigned short*)d_ws;
    unsigned short* wsB = (unsigned short*)((char*)d_ws + traj_bytes);

    int n_waves = B * NCHUNK * 2;        // 8192 sweep waves
    hipLaunchKernelGGL(bcjr_sweep_kernel, dim3(n_waves / 4), dim3(256), 0, stream,
                       llr_ch, llr_a, wsA, wsB);

    int n_thr = B * T_LEN;               // one thread per (b,t)
    hipLaunchKernelGGL(bcjr_llr_kernel, dim3(n_thr / 256), dim3(256), 0, stream,
                       llr_ch, llr_a, wsA, wsB, out);
}